// Round 1
// baseline (113.878 us; speedup 1.0000x reference)
//
#include <hip/hip_runtime.h>
#include <hip/hip_bf16.h>

typedef __bf16 bf16x8 __attribute__((ext_vector_type(8)));
typedef float  f32x4  __attribute__((ext_vector_type(4)));

#define B_ROWS 64
#define NSEG   39
#define NCAT   26
#define VOCAB  100000
#define DIM    64
#define HID    512
#define KTOT   2496   // 39*64

__device__ __forceinline__ bf16x8 pack8(const float v[8]) {
    bf16x8 r;
#pragma unroll
    for (int i = 0; i < 8; ++i) r[i] = (__bf16)v[i];
    return r;
}

__global__ void w1_to_bf16(const float* __restrict__ w1, ushort* __restrict__ w1b, int n4) {
    int i = blockIdx.x * blockDim.x + threadIdx.x;
    if (i >= n4) return;
    f32x4 v = ((const f32x4*)w1)[i];
    ushort4 o;
    o.x = __builtin_bit_cast(unsigned short, (__bf16)v[0]);
    o.y = __builtin_bit_cast(unsigned short, (__bf16)v[1]);
    o.z = __builtin_bit_cast(unsigned short, (__bf16)v[2]);
    o.w = __builtin_bit_cast(unsigned short, (__bf16)v[3]);
    ((ushort4*)w1b)[i] = o;
}

template<bool W1BF>
__global__ __launch_bounds__(512, 1)
void fused_net(const float* __restrict__ x,      // B x 39
               const float* __restrict__ emb,    // 26 x V x 64
               const float* __restrict__ ctsW,   // 13 x 64
               const float* __restrict__ ctsB,   // 13 x 64
               const void*  __restrict__ W1p,    // 512 x 2496 (bf16 or f32)
               const float* __restrict__ b1,     // 512
               const float* __restrict__ W2,     // 512
               const float* __restrict__ b2,     // 1
               float* __restrict__ out)          // B
{
    const int tid  = threadIdx.x;
    const int lane = tid & 63;
    const int wave = tid >> 6;
    const int m0   = blockIdx.x * B_ROWS;

    __shared__ float xs[B_ROWS * NSEG];                    // 9984 B
    __shared__ __align__(16) ushort Abuf[2][B_ROWS * 64];  // 2 x 8 KB, bf16 bits, swizzled
    __shared__ float hsum[B_ROWS];

    // preload this tile's x rows (indices + cts values)
    for (int e = tid; e < B_ROWS * NSEG; e += 512)
        xs[e] = x[(size_t)m0 * NSEG + e];
    if (tid < B_ROWS) hsum[tid] = 0.f;

    // epilogue constants: this lane's 4 n-columns
    float b1v[4], w2v[4];
#pragma unroll
    for (int ni = 0; ni < 4; ++ni) {
        int n = wave * 64 + ni * 16 + (lane & 15);
        b1v[ni] = b1[n];
        w2v[ni] = W2[n];
    }

    __syncthreads();

    // staging geometry: thread -> (row r, 16B slot s); content chunk c = s ^ (r&7) (XOR swizzle)
    const int r = tid >> 3;
    const int s = tid & 7;
    const int c = s ^ (r & 7);

    f32x4 s0, s1, s2, s3;
    float sxv = 0.f;

    auto issue = [&](int t) {
        if (t < NCAT) {
            int idx = (int)xs[r * NSEG + t];
            const float* p = emb + ((size_t)t * VOCAB + (size_t)idx) * DIM + c * 8;
            s0 = *(const f32x4*)p;
            s1 = *(const f32x4*)(p + 4);
        } else {
            int jj = t - NCAT;
            const float* wp = ctsW + jj * DIM + c * 8;
            const float* bp = ctsB + jj * DIM + c * 8;
            s0 = *(const f32x4*)wp;
            s1 = *(const f32x4*)(wp + 4);
            s2 = *(const f32x4*)bp;
            s3 = *(const f32x4*)(bp + 4);
            sxv = xs[r * NSEG + t];
        }
    };

    auto writeA = [&](int t, int buf) {
        float vv[8];
        if (t < NCAT) {
            vv[0]=s0[0]; vv[1]=s0[1]; vv[2]=s0[2]; vv[3]=s0[3];
            vv[4]=s1[0]; vv[5]=s1[1]; vv[6]=s1[2]; vv[7]=s1[3];
            if (t >= 1) {
#pragma unroll
                for (int k = 0; k < 8; ++k) vv[k] = fmaxf(vv[k], 0.f);
            }
        } else {
            float w[8] = { s0[0],s0[1],s0[2],s0[3], s1[0],s1[1],s1[2],s1[3] };
            float bb[8] = { s2[0],s2[1],s2[2],s2[3], s3[0],s3[1],s3[2],s3[3] };
#pragma unroll
            for (int k = 0; k < 8; ++k) vv[k] = fmaxf(fmaf(sxv, w[k], bb[k]), 0.f);
        }
        *(bf16x8*)&Abuf[buf][r * 64 + s * 8] = pack8(vv);
    };

    // per-lane W1 row offsets (elements)
    unsigned bbase[4];
#pragma unroll
    for (int ni = 0; ni < 4; ++ni)
        bbase[ni] = (unsigned)(wave * 64 + ni * 16 + (lane & 15)) * KTOT + ((lane >> 4) << 3);

    const ushort* W1b = (const ushort*)W1p;
    const float*  W1f = (const float*)W1p;

    f32x4 acc[4][4];
#pragma unroll
    for (int mi = 0; mi < 4; ++mi)
#pragma unroll
        for (int ni = 0; ni < 4; ++ni)
            acc[mi][ni] = (f32x4){0.f, 0.f, 0.f, 0.f};

    issue(0);

    for (int t = 0; t < NSEG; ++t) {
        const int buf = t & 1;
        writeA(t, buf);          // consumes stage regs for t (vmcnt wait by compiler)
        __syncthreads();

        // B fragments for step t (direct from global/L2)
        bf16x8 bfr[2][4];
#pragma unroll
        for (int ks = 0; ks < 2; ++ks)
#pragma unroll
            for (int ni = 0; ni < 4; ++ni) {
                unsigned off = bbase[ni] + t * 64 + ks * 32;
                if constexpr (W1BF) {
                    bfr[ks][ni] = *(const bf16x8*)(W1b + off);
                } else {
                    f32x4 u0 = *(const f32x4*)(W1f + off);
                    f32x4 u1 = *(const f32x4*)(W1f + off + 4);
                    float vv[8] = { u0[0],u0[1],u0[2],u0[3], u1[0],u1[1],u1[2],u1[3] };
                    bfr[ks][ni] = pack8(vv);
                }
            }

        // prefetch next segment's A data (lands during this step's MFMAs)
        if (t + 1 < NSEG) issue(t + 1);

#pragma unroll
        for (int ks = 0; ks < 2; ++ks) {
            bf16x8 afr[4];
#pragma unroll
            for (int mi = 0; mi < 4; ++mi) {
                int R = mi * 16 + (lane & 15);
                int C = ks * 4 + (lane >> 4);
                afr[mi] = *(const bf16x8*)&Abuf[buf][R * 64 + ((C ^ (R & 7)) << 3)];
            }
#pragma unroll
            for (int ni = 0; ni < 4; ++ni)
#pragma unroll
                for (int mi = 0; mi < 4; ++mi)
                    acc[mi][ni] = __builtin_amdgcn_mfma_f32_16x16x32_bf16(
                        afr[mi], bfr[ks][ni], acc[mi][ni], 0, 0, 0);
        }
    }

    // epilogue: out = exp(relu(acc + b1) @ W2 + b2), fully in-block
    float p[4][4];
#pragma unroll
    for (int mi = 0; mi < 4; ++mi)
#pragma unroll
        for (int rg = 0; rg < 4; ++rg) p[mi][rg] = 0.f;

#pragma unroll
    for (int mi = 0; mi < 4; ++mi)
#pragma unroll
        for (int ni = 0; ni < 4; ++ni)
#pragma unroll
            for (int rg = 0; rg < 4; ++rg) {
                float h = fmaxf(acc[mi][ni][rg] + b1v[ni], 0.f);
                p[mi][rg] = fmaf(h, w2v[ni], p[mi][rg]);
            }

#pragma unroll
    for (int m = 1; m < 16; m <<= 1)
#pragma unroll
        for (int mi = 0; mi < 4; ++mi)
#pragma unroll
            for (int rg = 0; rg < 4; ++rg)
                p[mi][rg] += __shfl_xor(p[mi][rg], m, 64);

    if ((lane & 15) == 0) {
        int g = lane >> 4;
#pragma unroll
        for (int mi = 0; mi < 4; ++mi)
#pragma unroll
            for (int rg = 0; rg < 4; ++rg)
                atomicAdd(&hsum[mi * 16 + g * 4 + rg], p[mi][rg]);
    }
    __syncthreads();

    if (tid < B_ROWS) out[m0 + tid] = expf(hsum[tid] + b2[0]);
}

extern "C" void kernel_launch(void* const* d_in, const int* in_sizes, int n_in,
                              void* d_out, int out_size, void* d_ws, size_t ws_size,
                              hipStream_t stream) {
    const float* x    = (const float*)d_in[0];
    const float* emb  = (const float*)d_in[1];
    const float* ctsW = (const float*)d_in[2];
    const float* ctsB = (const float*)d_in[3];
    const float* W1   = (const float*)d_in[4];
    const float* b1   = (const float*)d_in[5];
    const float* W2   = (const float*)d_in[6];
    const float* b2   = (const float*)d_in[7];
    float* out = (float*)d_out;

    const int Bn = in_sizes[0] / NSEG;           // 16384
    const int nblk = Bn / B_ROWS;                // 256
    const size_t w1b_bytes = (size_t)HID * KTOT * sizeof(unsigned short);

    if (ws_size >= w1b_bytes) {
        ushort* W1b = (ushort*)d_ws;
        int n4 = HID * KTOT / 4;
        w1_to_bf16<<<(n4 + 255) / 256, 256, 0, stream>>>(W1, W1b, n4);
        fused_net<true><<<nblk, 512, 0, stream>>>(x, emb, ctsW, ctsB, (const void*)W1b,
                                                  b1, W2, b2, out);
    } else {
        fused_net<false><<<nblk, 512, 0, stream>>>(x, emb, ctsW, ctsB, (const void*)W1,
                                                   b1, W2, b2, out);
    }
}

// Round 2
// 94.493 us; speedup vs baseline: 1.2052x; 1.2052x over previous
//
#include <hip/hip_runtime.h>
#include <hip/hip_bf16.h>

typedef __bf16 bf16x8 __attribute__((ext_vector_type(8)));
typedef float  f32x4  __attribute__((ext_vector_type(4)));

#define B_ROWS 64
#define NSEG   39
#define NCAT   26
#define NCTS   13
#define VOCAB  100000
#define DIM    64
#define HID    512
#define KTOT   2496   // 39*64
#define RDEPTH 4      // gather prefetch depth (must be even)

__device__ __forceinline__ bf16x8 pack8(const float v[8]) {
    bf16x8 r;
#pragma unroll
    for (int i = 0; i < 8; ++i) r[i] = (__bf16)v[i];
    return r;
}

__global__ void w1_to_bf16(const float* __restrict__ w1, ushort* __restrict__ w1b, int n4) {
    int i = blockIdx.x * blockDim.x + threadIdx.x;
    if (i >= n4) return;
    f32x4 v = ((const f32x4*)w1)[i];
    ushort4 o;
    o.x = __builtin_bit_cast(unsigned short, (__bf16)v[0]);
    o.y = __builtin_bit_cast(unsigned short, (__bf16)v[1]);
    o.z = __builtin_bit_cast(unsigned short, (__bf16)v[2]);
    o.w = __builtin_bit_cast(unsigned short, (__bf16)v[3]);
    ((ushort4*)w1b)[i] = o;
}

template<bool W1BF>
__global__ __launch_bounds__(512, 1)
void fused_net(const float* __restrict__ x,      // B x 39
               const float* __restrict__ emb,    // 26 x V x 64
               const float* __restrict__ ctsW,   // 13 x 64
               const float* __restrict__ ctsB,   // 13 x 64
               const void*  __restrict__ W1p,    // 512 x 2496 (bf16 or f32)
               const float* __restrict__ b1,     // 512
               const float* __restrict__ W2,     // 512
               const float* __restrict__ b2,     // 1
               float* __restrict__ out)          // B
{
    const int tid  = threadIdx.x;
    const int lane = tid & 63;
    const int wave = tid >> 6;
    const int m0   = blockIdx.x * B_ROWS;

    __shared__ float xs[B_ROWS * NSEG];                    // 9984 B
    __shared__ float ctsw_s[NCTS * DIM];                   // 3328 B
    __shared__ float ctsb_s[NCTS * DIM];                   // 3328 B
    __shared__ __align__(16) ushort Abuf[2][B_ROWS * 64];  // 2 x 8 KB
    __shared__ float hsum[B_ROWS];

    for (int e = tid; e < B_ROWS * NSEG; e += 512)
        xs[e] = x[(size_t)m0 * NSEG + e];
    for (int e = tid; e < NCTS * DIM; e += 512) {
        ctsw_s[e] = ctsW[e];
        ctsb_s[e] = ctsB[e];
    }
    if (tid < B_ROWS) hsum[tid] = 0.f;

    float b1v[4], w2v[4];
#pragma unroll
    for (int ni = 0; ni < 4; ++ni) {
        int n = wave * 64 + ni * 16 + (lane & 15);
        b1v[ni] = b1[n];
        w2v[ni] = W2[n];
    }

    __syncthreads();

    // staging geometry: thread -> (row r, 16B slot s); content chunk c = s ^ (r&7)
    const int r = tid >> 3;
    const int s = tid & 7;
    const int c = s ^ (r & 7);

    // per-lane W1 row offsets (elements)
    unsigned bbase[4];
#pragma unroll
    for (int ni = 0; ni < 4; ++ni)
        bbase[ni] = (unsigned)(wave * 64 + ni * 16 + (lane & 15)) * KTOT + ((lane >> 4) << 3);

    const ushort* W1b = (const ushort*)W1p;
    const float*  W1f = (const float*)W1p;

    // gather register ring (statically indexed via unrolled loop)
    f32x4 g0[RDEPTH], g1[RDEPTH];

    auto issueCat = [&](int t, int j) {
        int idx = (int)xs[r * NSEG + t];
        const float* p = emb + ((size_t)t * VOCAB + (size_t)idx) * DIM + c * 8;
        g0[j] = __builtin_nontemporal_load((const f32x4*)p);
        g1[j] = __builtin_nontemporal_load(((const f32x4*)p) + 1);
    };

    auto writeA = [&](int t, int j, int buf) {
        float vv[8];
        if (t < NCAT) {
#pragma unroll
            for (int k = 0; k < 4; ++k) { vv[k] = g0[j][k]; vv[4 + k] = g1[j][k]; }
            if (t >= 1) {
#pragma unroll
                for (int k = 0; k < 8; ++k) vv[k] = fmaxf(vv[k], 0.f);
            }
        } else {
            int jj = t - NCAT;
            float sx = xs[r * NSEG + t];
            f32x4 w0 = *(const f32x4*)&ctsw_s[jj * DIM + c * 8];
            f32x4 w1 = *(const f32x4*)&ctsw_s[jj * DIM + c * 8 + 4];
            f32x4 q0 = *(const f32x4*)&ctsb_s[jj * DIM + c * 8];
            f32x4 q1 = *(const f32x4*)&ctsb_s[jj * DIM + c * 8 + 4];
#pragma unroll
            for (int k = 0; k < 4; ++k) {
                vv[k]     = fmaxf(fmaf(sx, w0[k], q0[k]), 0.f);
                vv[4 + k] = fmaxf(fmaf(sx, w1[k], q1[k]), 0.f);
            }
        }
        *(bf16x8*)&Abuf[buf][r * 64 + s * 8] = pack8(vv);
    };

    bf16x8 bfr[2][2][4];  // [set][ks][ni]
    auto loadB = [&](int t, int set) {
#pragma unroll
        for (int ks = 0; ks < 2; ++ks)
#pragma unroll
            for (int ni = 0; ni < 4; ++ni) {
                unsigned off = bbase[ni] + t * 64 + ks * 32;
                if constexpr (W1BF) {
                    bfr[set][ks][ni] = *(const bf16x8*)(W1b + off);
                } else {
                    f32x4 u0 = *(const f32x4*)(W1f + off);
                    f32x4 u1 = *(const f32x4*)(W1f + off + 4);
                    float vv[8] = { u0[0],u0[1],u0[2],u0[3], u1[0],u1[1],u1[2],u1[3] };
                    bfr[set][ks][ni] = pack8(vv);
                }
            }
    };

    f32x4 acc[4][4];
#pragma unroll
    for (int mi = 0; mi < 4; ++mi)
#pragma unroll
        for (int ni = 0; ni < 4; ++ni)
            acc[mi][ni] = (f32x4){0.f, 0.f, 0.f, 0.f};

    // prologue: fill gather ring + first B set
#pragma unroll
    for (int j = 0; j < RDEPTH; ++j) issueCat(j, j);
    loadB(0, 0);

    for (int tt = 0; tt < NSEG; tt += RDEPTH) {
#pragma unroll
        for (int j = 0; j < RDEPTH; ++j) {
            const int t = tt + j;
            if (t < NSEG) {
                writeA(t, j, j & 1);
                // drain LDS ops only; global loads stay in flight across the barrier
                asm volatile("s_waitcnt lgkmcnt(0)" ::: "memory");
                __builtin_amdgcn_s_barrier();
                __builtin_amdgcn_sched_barrier(0);

                if (t + 1 < NSEG) loadB(t + 1, (j + 1) & 1);
                if (t + RDEPTH < NCAT) issueCat(t + RDEPTH, j);

#pragma unroll
                for (int ks = 0; ks < 2; ++ks) {
                    bf16x8 afr[4];
#pragma unroll
                    for (int mi = 0; mi < 4; ++mi) {
                        int R = mi * 16 + (lane & 15);
                        int C = ks * 4 + (lane >> 4);
                        afr[mi] = *(const bf16x8*)&Abuf[j & 1][R * 64 + ((C ^ (R & 7)) << 3)];
                    }
#pragma unroll
                    for (int ni = 0; ni < 4; ++ni)
#pragma unroll
                        for (int mi = 0; mi < 4; ++mi)
                            acc[mi][ni] = __builtin_amdgcn_mfma_f32_16x16x32_bf16(
                                afr[mi], bfr[j & 1][ks][ni], acc[mi][ni], 0, 0, 0);
                }
            }
        }
    }

    // epilogue: out = exp(relu(acc + b1) @ W2 + b2), fully in-block
    float p[4][4];
#pragma unroll
    for (int mi = 0; mi < 4; ++mi)
#pragma unroll
        for (int rg = 0; rg < 4; ++rg) p[mi][rg] = 0.f;

#pragma unroll
    for (int mi = 0; mi < 4; ++mi)
#pragma unroll
        for (int ni = 0; ni < 4; ++ni)
#pragma unroll
            for (int rg = 0; rg < 4; ++rg) {
                float h = fmaxf(acc[mi][ni][rg] + b1v[ni], 0.f);
                p[mi][rg] = fmaf(h, w2v[ni], p[mi][rg]);
            }

#pragma unroll
    for (int m = 1; m < 16; m <<= 1)
#pragma unroll
        for (int mi = 0; mi < 4; ++mi)
#pragma unroll
            for (int rg = 0; rg < 4; ++rg)
                p[mi][rg] += __shfl_xor(p[mi][rg], m, 64);

    if ((lane & 15) == 0) {
        int g = lane >> 4;
#pragma unroll
        for (int mi = 0; mi < 4; ++mi)
#pragma unroll
            for (int rg = 0; rg < 4; ++rg)
                atomicAdd(&hsum[mi * 16 + g * 4 + rg], p[mi][rg]);
    }
    __syncthreads();

    if (tid < B_ROWS) out[m0 + tid] = expf(hsum[tid] + b2[0]);
}

extern "C" void kernel_launch(void* const* d_in, const int* in_sizes, int n_in,
                              void* d_out, int out_size, void* d_ws, size_t ws_size,
                              hipStream_t stream) {
    const float* x    = (const float*)d_in[0];
    const float* emb  = (const float*)d_in[1];
    const float* ctsW = (const float*)d_in[2];
    const float* ctsB = (const float*)d_in[3];
    const float* W1   = (const float*)d_in[4];
    const float* b1   = (const float*)d_in[5];
    const float* W2   = (const float*)d_in[6];
    const float* b2   = (const float*)d_in[7];
    float* out = (float*)d_out;

    const int Bn = in_sizes[0] / NSEG;           // 16384
    const int nblk = Bn / B_ROWS;                // 256
    const size_t w1b_bytes = (size_t)HID * KTOT * sizeof(unsigned short);

    if (ws_size >= w1b_bytes) {
        ushort* W1b = (ushort*)d_ws;
        int n4 = HID * KTOT / 4;
        w1_to_bf16<<<(n4 + 255) / 256, 256, 0, stream>>>(W1, W1b, n4);
        fused_net<true><<<nblk, 512, 0, stream>>>(x, emb, ctsW, ctsB, (const void*)W1b,
                                                  b1, W2, b2, out);
    } else {
        fused_net<false><<<nblk, 512, 0, stream>>>(x, emb, ctsW, ctsB, (const void*)W1,
                                                   b1, W2, b2, out);
    }
}